// Round 2
// 141.545 us; speedup vs baseline: 1.0501x; 1.0501x over previous
//
#include <hip/hip_runtime.h>
#include <math.h>

#define B_ 4
#define S_ 2048
#define D_ 128
#define EPSF 1e-5f
#define BN 128
#define BN2 64
#define PSB 272   // Ps row stride in bytes: 16B-aligned rows

typedef __attribute__((ext_vector_type(8))) short short8;
typedef __attribute__((ext_vector_type(4))) float f32x4;

static __device__ __forceinline__ unsigned short f2bf(float f) {
    unsigned u = __float_as_uint(f);
    return (unsigned short)((u + 0x7fffu + ((u >> 16) & 1u)) >> 16);
}

static __device__ __forceinline__ void gload_lds16(const void* g, void* l) {
    __builtin_amdgcn_global_load_lds((const __attribute__((address_space(1))) unsigned*)g,
                                     (__attribute__((address_space(3))) unsigned*)l, 16, 0, 0);
}

// ===================== pre-pass kernels (shared by both paths) =====================
// ws bytes: [0,32K) qn, [32K,64K) kn, [64K,96K) lws, [96K,160K) qng, [160K,224K) kng,
//           [224K..) Qb(2M) Kb(2M) Vtb(2M) [Opart(8M) Pws(33.5M)]

__global__ __launch_bounds__(256) void convqk_kernel(const float* __restrict__ q,
                                                     const float* __restrict__ k,
                                                     const float* __restrict__ cp,
                                                     float* __restrict__ qn, float* __restrict__ kn,
                                                     float* __restrict__ lws,
                                                     float2* __restrict__ qng, float2* __restrict__ kng,
                                                     unsigned* __restrict__ Qb, unsigned* __restrict__ Kb) {
    int row = blockIdx.x * 4 + (threadIdx.x >> 6);   // one wave per row, 16384 rows
    int lane = threadIdx.x & 63;
    const int NR = B_ * S_;
    const float cc = cp[0];
    bool isQ = row < NR;
    int r = isQ ? row : row - NR;
    float2 v = ((const float2*)(isQ ? q : k))[(size_t)r * 64 + lane];
    unsigned pk = (unsigned)f2bf(v.x) | ((unsigned)f2bf(v.y) << 16);
    float nrm = v.x * v.x + v.y * v.y;
#pragma unroll
    for (int m = 1; m <= 32; m <<= 1) nrm += __shfl_xor(nrm, m, 64);
    if (isQ) {
        Qb[(size_t)r * 64 + lane] = pk;              // plain row-major
        if (lane == 0) {
            qn[r] = nrm;
            qng[r] = make_float2(nrm, 2.f * cc * __builtin_amdgcn_rcpf(1.f - cc * nrm));
        }
        if (lane == 1) lws[r] = 0.f;                 // zero l accumulator for attn atomics
    } else {
        int c = lane >> 2;                           // 16B chunk index 0..15
        int cs = c ^ (r & 7);                        // bake LDS bank swizzle into global layout
        Kb[(size_t)r * 64 + cs * 4 + (lane & 3)] = pk;
        if (lane == 0) {
            kn[r] = nrm;
            kng[r] = make_float2(nrm, __builtin_amdgcn_rcpf(1.f - cc * nrm));
        }
    }
}

__global__ __launch_bounds__(256) void convv_kernel(const float* __restrict__ v, uint4* __restrict__ Vtb) {
    __shared__ unsigned short Vs[128 * 132];
    int b = blockIdx.x >> 4;
    int t = blockIdx.x & 15;
    int tid = threadIdx.x;
    const float* src = v + ((size_t)b * S_ + t * 128) * D_;
    int d4 = tid & 31, key0 = tid >> 5;
#pragma unroll
    for (int it = 0; it < 16; ++it) {
        int key = key0 + it * 8;
        float4 f = *(const float4*)(src + (size_t)key * D_ + d4 * 4);
        unsigned short* dst = &Vs[key * 132 + d4 * 4];
        dst[0] = f2bf(f.x); dst[1] = f2bf(f.y); dst[2] = f2bf(f.z); dst[3] = f2bf(f.w);
    }
    __syncthreads();
    uint4* tile = Vtb + (size_t)blockIdx.x * (128 * 16);   // [tile][d=128][16 x 16B chunks]
    int d = tid & 127;
    int cl = tid >> 7;
#pragma unroll
    for (int it = 0; it < 8; ++it) {
        int c = cl + it * 2;
        int kb = c * 8;
        unsigned short e0 = Vs[(kb + 0) * 132 + d], e1 = Vs[(kb + 1) * 132 + d];
        unsigned short e2 = Vs[(kb + 2) * 132 + d], e3 = Vs[(kb + 3) * 132 + d];
        unsigned short e4 = Vs[(kb + 4) * 132 + d], e5 = Vs[(kb + 5) * 132 + d];
        unsigned short e6 = Vs[(kb + 6) * 132 + d], e7 = Vs[(kb + 7) * 132 + d];
        uint4 o;
        o.x = (unsigned)e0 | ((unsigned)e1 << 16);
        o.y = (unsigned)e2 | ((unsigned)e3 << 16);
        o.z = (unsigned)e4 | ((unsigned)e5 << 16);
        o.w = (unsigned)e6 | ((unsigned)e7 << 16);
        tile[d * 16 + (c ^ (d & 7))] = o;
    }
}

// ===================== v3: double-buffered pipelined split-t MFMA attention =====================
// BN2=64 key tiles, K/V double-buffered in LDS. K-stage + kng-load issued at iter top (hidden
// under QK+dist, drained by barrier A's implicit vmcnt(0)); V-stage issued after barrier A
// (hidden under PV, drained by barrier B). 2 barriers/iter. Softmax denominator accumulated
// in registers across all 16 iterations; one reduction at the end.

__global__ __launch_bounds__(512, 2) void hattn3_kernel(
    const unsigned short* __restrict__ Qb, const char* __restrict__ Kb, const char* __restrict__ Vtb,
    const float2* __restrict__ qng, const float2* __restrict__ kng,
    const float* __restrict__ cp, const float* __restrict__ betap, const float* __restrict__ biasp,
    float* __restrict__ lws, float* __restrict__ Opart, uint4* __restrict__ Pws) {

    // LDS: Ks[2] @0/16384 (64 rows x 256B each), Vt[2] @32768/49152 (128 d-rows x 128B each),
    //      Ps @65536 (32 x 272B), yg[2] @74240/74752 (64 float2 each), xr @75264 (32 float2),
    //      l_row @75520 (32 f32). Total 75648 -> 2 blocks/CU.
    __shared__ __align__(1024) char smem[75648];
    char* PsB = smem + 65536;
    float* l_row = (float*)(smem + 75520);

    const int tid = threadIdx.x;
    const int lane = tid & 63, wave = tid >> 6;
    const int wm = wave & 1, wn = wave >> 1;         // wm: 16-row half; wn: 16-col / 32-d slice
    const int lm = lane & 15, quad = lane >> 4;

    const int th = blockIdx.x & 1;                   // t-half
    const int b = (blockIdx.x >> 1) & 3;
    const int rb = blockIdx.x >> 3;                  // 0..63
    const int s0 = rb * 32;
    const size_t bS = (size_t)b * S_;
    const int g0 = th * 16;                          // first 64-key tile of this half

    const float beta = betap[0], bias = biasp[0];
    const float cc = cp[0];
    const float beta_pos = fmaxf(beta, 0.f) + log1pf(__expf(-fabsf(beta)));
    const float sqrt_c = sqrtf(cc);
    const float bneg = -beta_pos / sqrt_c;           // p = 2^(bneg*log2(w) + bias2)
    const float bias2 = -bias * 1.442695040888963f;
    const float onepe = 1.f + EPSF;

    const char* KbBase = Kb + bS * 256;
    const char* VtBase = Vtb + (size_t)b * 16 * 32768;

    // ---- prologue: stage tile g0 into buffer 0 (full-wave gload_lds), norms via plain loads ----
    {
        const char* ks = KbBase + (size_t)g0 * 16384;
        const char* vs = VtBase + (size_t)(g0 >> 1) * 32768 + (size_t)(g0 & 1) * 128;
#pragma unroll
        for (int j = 0; j < 2; ++j) {
            int m = tid + j * 512;
            gload_lds16(ks + m * 16, smem + m * 16);
            gload_lds16(vs + (m >> 3) * 256 + (m & 7) * 16, smem + 32768 + m * 16);
        }
        if (tid < 64) {
            float2 y = kng[bS + (size_t)g0 * 64 + tid];
            *(float2*)(smem + 74240 + tid * 8) = y;
        }
        if (tid >= 64 && tid < 96) {
            float2 x = qng[bS + s0 + (tid - 64)];
            *(float2*)(smem + 75264 + (tid - 64) * 8) = x;
        }
        if (tid >= 96 && tid < 128) l_row[tid - 96] = 0.f;
    }

    // Q A-frags in registers (A: m=lane&15, k=quad*8+j)
    short8 aq[4];
    {
        const unsigned short* qrow = Qb + (bS + s0 + wm * 16 + lm) * D_;
#pragma unroll
        for (int ks = 0; ks < 4; ++ks)
            aq[ks] = *(const short8*)(qrow + ks * 32 + quad * 8);
    }

    f32x4 o0 = {0.f, 0.f, 0.f, 0.f}, o1 = {0.f, 0.f, 0.f, 0.f};
    float lacc[4] = {0.f, 0.f, 0.f, 0.f};

    __syncthreads();   // prologue staging drained (vmcnt(0)+lgkmcnt(0) implicit)

    int p = 0;
    const int n0 = wn * 16 + lm;                     // key col (QK) / yg index
    for (int it = 0; it < 16; ++it) {
        char* KsC = smem + p * 16384;
        char* VtC = smem + 32768 + p * 16384;
        const char* YGC = smem + 74240 + p * 512;

        // ---- issue next K tile into back buffer + kng load to regs (hidden under QK+dist) ----
        float2 ygn;
        if (it < 15) {
            int g = g0 + it + 1;
            const char* ks = KbBase + (size_t)g * 16384;
            char* kd = smem + (p ^ 1) * 16384;
#pragma unroll
            for (int j = 0; j < 2; ++j) {
                int off = (tid + j * 512) * 16;
                gload_lds16(ks + off, kd + off);
            }
            if (tid < 64) ygn = kng[bS + (size_t)g * 64 + tid];
        }

        // ---- S = Q K^T (wave tile 16x16) ----
        f32x4 acc = {0.f, 0.f, 0.f, 0.f};
#pragma unroll
        for (int ks = 0; ks < 4; ++ks) {
            int c = ks * 4 + quad;
            short8 bk = *(const short8*)(KsC + n0 * 256 + ((c ^ (n0 & 7)) * 16));
            acc = __builtin_amdgcn_mfma_f32_16x16x32_bf16(aq[ks], bk, acc, 0, 0, 0);
        }

        // ---- dist -> p = exp2(bneg*log2(arg+sqrt(arg^2-1)) + bias2), unnormalized ----
        {
            float2 yg = *(const float2*)(YGC + n0 * 8);
#pragma unroll
            for (int r = 0; r < 4; ++r) {
                int row = wm * 16 + quad * 4 + r;    // C/D layout: row=(lane>>4)*4+reg
                float2 xr = *(const float2*)(smem + 75264 + row * 8);
                float diff = fmaf(-2.f, acc[r], xr.x + yg.x);
                float arg = fmaf(diff * yg.y, xr.y, 1.f);
                arg = fmaxf(arg, onepe);
                float w = arg + sqrtf(fmaf(arg, arg, -1.f));
                float pv = __builtin_amdgcn_exp2f(fmaf(bneg, __builtin_amdgcn_logf(w), bias2));
                *(unsigned short*)(PsB + row * PSB + n0 * 2) = f2bf(pv);
                lacc[r] += pv;
            }
        }
        __syncthreads();   // A: Ps visible; K back-buffer staged (implicit vmcnt drain)

        // ---- issue next V tile into back buffer + store kng to LDS (hidden under PV) ----
        if (it < 15) {
            int g = g0 + it + 1;
            const char* vs = VtBase + (size_t)(g >> 1) * 32768 + (size_t)(g & 1) * 128;
            char* vd = smem + 32768 + (p ^ 1) * 16384;
#pragma unroll
            for (int j = 0; j < 2; ++j) {
                int m = tid + j * 512;
                gload_lds16(vs + (m >> 3) * 256 + (m & 7) * 16, vd + m * 16);
            }
            if (tid < 64) *(float2*)(smem + 74240 + (p ^ 1) * 512 + tid * 8) = ygn;
        }

        // ---- coalesced P tile -> global bf16 (32x64 = 4KB = 256 x uint4) ----
        if (tid < 256) {
            int row = tid >> 3, ch = tid & 7;
            uint4 pv = *(const uint4*)(PsB + row * PSB + ch * 16);
            Pws[(((bS + s0 + row) * S_ + (size_t)(g0 + it) * 64) >> 3) + ch] = pv;
        }

        // ---- O += P V (wave tile 16 rows x 32 d) ----
#pragma unroll
        for (int ks2 = 0; ks2 < 2; ++ks2) {
            short8 ap = *(const short8*)(PsB + (wm * 16 + lm) * PSB + (ks2 * 32 + quad * 8) * 2);
            int d0 = wn * 32 + lm;
            int lo = ks2 * 4 + quad;
            short8 v0 = *(const short8*)(VtC + d0 * 128 + ((lo ^ (d0 & 7)) * 16));
            int d1 = d0 + 16;
            short8 v1 = *(const short8*)(VtC + d1 * 128 + ((lo ^ (d1 & 7)) * 16));
            o0 = __builtin_amdgcn_mfma_f32_16x16x32_bf16(ap, v0, o0, 0, 0, 0);
            o1 = __builtin_amdgcn_mfma_f32_16x16x32_bf16(ap, v1, o1, 0, 0, 0);
        }
        __syncthreads();   // B: V back-buffer + yg store visible; Ps/Vt[p] readers done
        p ^= 1;
    }

    // ---- one-shot l reduction (registers -> LDS -> global) ----
#pragma unroll
    for (int r = 0; r < 4; ++r) {
        float s = lacc[r];
#pragma unroll
        for (int m = 1; m <= 8; m <<= 1) s += __shfl_xor(s, m, 64);
        if (lm == 0) atomicAdd(&l_row[wm * 16 + quad * 4 + r], s);
    }
    __syncthreads();

    // ---- write partial O (unnormalized) + accumulate l globally ----
    float* op = Opart + (size_t)th * (B_ * S_ * D_) + (bS + s0) * D_;
#pragma unroll
    for (int r = 0; r < 4; ++r) {
        int row = wm * 16 + quad * 4 + r;
        op[(size_t)row * D_ + wn * 32 + lm] = o0[r];
        op[(size_t)row * D_ + wn * 32 + 16 + lm] = o1[r];
    }
    if (tid < 32) atomicAdd(&lws[bS + s0 + tid], l_row[tid]);
}

// combine partial O, normalize, exp-map
__global__ __launch_bounds__(256) void hepi_kernel(const float* __restrict__ Opart,
                                                   const float* __restrict__ lws,
                                                   const float* __restrict__ cp,
                                                   float* __restrict__ hout) {
    int row = blockIdx.x * 4 + (threadIdx.x >> 6);   // one wave per row
    int lane = threadIdx.x & 63;
    const float cc = cp[0];
    const float sqrt_c = sqrtf(cc);
    float2 a = ((const float2*)(Opart + (size_t)row * D_))[lane];
    float2 b = ((const float2*)(Opart + (size_t)(B_ * S_ * D_) + (size_t)row * D_))[lane];
    float linv = 1.f / lws[row];
    float x0 = (a.x + b.x) * linv;
    float x1 = (a.y + b.y) * linv;
    float np = x0 * x0 + x1 * x1;
#pragma unroll
    for (int m = 1; m <= 32; m <<= 1) np += __shfl_xor(np, m, 64);
    float vn = fmaxf(sqrtf(np), EPSF);
    float aa = sqrt_c * vn;
    float t = 1.f - 2.f / (__expf(2.f * aa) + 1.f);  // tanh(aa)
    float sc = t / aa;                                // tanh(sqrt_c*vn)/sqrt_c/vn
    float2 o = {x0 * sc, x1 * sc};
    ((float2*)(hout + (size_t)row * D_))[lane] = o;
}

// expand bf16 P -> normalized fp32 W
__global__ __launch_bounds__(256) void wnorm2_kernel(const uint4* __restrict__ Pws,
                                                     const float* __restrict__ lws,
                                                     float* __restrict__ w) {
    size_t idx = (size_t)blockIdx.x * 256 + threadIdx.x;   // uint4 index (8 bf16)
    int row = (int)(idx >> 8);                             // 256 uint4 per 2048-col row
    float linv = 1.f / lws[row];
    uint4 u = Pws[idx];
    float4 f0, f1;
    f0.x = __uint_as_float(u.x << 16) * linv;
    f0.y = __uint_as_float(u.x & 0xffff0000u) * linv;
    f0.z = __uint_as_float(u.y << 16) * linv;
    f0.w = __uint_as_float(u.y & 0xffff0000u) * linv;
    f1.x = __uint_as_float(u.z << 16) * linv;
    f1.y = __uint_as_float(u.z & 0xffff0000u) * linv;
    f1.z = __uint_as_float(u.w << 16) * linv;
    f1.w = __uint_as_float(u.w & 0xffff0000u) * linv;
    float4* out = (float4*)w + idx * 2;
    out[0] = f0;
    out[1] = f1;
}

// ===================== round-2 path (proven, ws fallback) =====================

__global__ __launch_bounds__(512, 2) void hattn_kernel(
    const unsigned short* __restrict__ Qb, const char* __restrict__ Kb, const char* __restrict__ Vtb,
    const float* __restrict__ qn, const float* __restrict__ kn,
    const float* __restrict__ cp, const float* __restrict__ betap, const float* __restrict__ biasp,
    float* __restrict__ lws, float* __restrict__ houtg, float* __restrict__ woutg) {

    __shared__ __align__(1024) char smem[75136];
    char* KsB = smem;
    char* VtB = smem + 32768;
    char* PsB = smem + 65536;
    float* kn_s  = (float*)(smem + 74240);
    float* qn_s  = (float*)(smem + 74752);
    float* l_row = (float*)(smem + 74880);
    float* nsq_s = (float*)(smem + 75008);

    const int tid = threadIdx.x;
    const int lane = tid & 63, wave = tid >> 6;
    const int wm = wave & 1, wn = wave >> 1;
    const int lm = lane & 15, quad = lane >> 4;

    int xcd = blockIdx.x & 7;
    int b = xcd >> 1;
    int rb = (blockIdx.x >> 3) * 2 + (xcd & 1);
    int s0 = rb * 32;
    const size_t bS = (size_t)b * S_;

    const float cc = cp[0], beta = betap[0], bias = biasp[0];
    const float beta_pos = fmaxf(beta, 0.f) + log1pf(__expf(-fabsf(beta)));
    const float sqrt_c = sqrtf(cc);
    const float inv_sqrt_c = 1.f / sqrt_c;

    if (tid < 32) {
        qn_s[tid] = qn[bS + s0 + tid];
        l_row[tid] = 0.f;
        nsq_s[tid] = 0.f;
    }

    short8 aq[4];
    {
        const unsigned short* qrow = Qb + (bS + s0 + wm * 16 + lm) * D_;
#pragma unroll
        for (int ks = 0; ks < 4; ++ks)
            aq[ks] = *(const short8*)(qrow + ks * 32 + quad * 8);
    }

    f32x4 o0 = {0.f, 0.f, 0.f, 0.f}, o1 = {0.f, 0.f, 0.f, 0.f};

    const char* KbBase = Kb + bS * 256;
    const char* VtBase = Vtb + (size_t)b * 16 * 32768;

    for (int t = 0; t < S_ / BN; ++t) {
        int t0 = t * BN;
        __syncthreads();
        {
            const uint4* ksrc = (const uint4*)(KbBase + (size_t)t0 * 256);
            const uint4* vsrc = (const uint4*)(VtBase + (size_t)t * 32768);
            uint4* kd = (uint4*)KsB;
            uint4* vd = (uint4*)VtB;
#pragma unroll
            for (int i = 0; i < 4; ++i) {
                kd[tid + i * 512] = ksrc[tid + i * 512];
                vd[tid + i * 512] = vsrc[tid + i * 512];
            }
            if (tid < BN) kn_s[tid] = kn[bS + t0 + tid];
        }
        __syncthreads();

        f32x4 acc0 = {0.f, 0.f, 0.f, 0.f}, acc1 = {0.f, 0.f, 0.f, 0.f};
#pragma unroll
        for (int ks = 0; ks < 4; ++ks) {
            int n0 = wn * 32 + lm;
            int c = ks * 4 + quad;
            short8 b0 = *(const short8*)(KsB + n0 * 256 + ((c ^ (n0 & 7)) * 16));
            int n1 = n0 + 16;
            short8 b1 = *(const short8*)(KsB + n1 * 256 + ((c ^ (n1 & 7)) * 16));
            acc0 = __builtin_amdgcn_mfma_f32_16x16x32_bf16(aq[ks], b0, acc0, 0, 0, 0);
            acc1 = __builtin_amdgcn_mfma_f32_16x16x32_bf16(aq[ks], b1, acc1, 0, 0, 0);
        }

        float lp[4];
#pragma unroll
        for (int r = 0; r < 4; ++r) {
            int row = wm * 16 + quad * 4 + r;
            float xn = qn_s[row];
            float fx = 1.f - cc * xn;
            float p0, p1;
#pragma unroll
            for (int nt = 0; nt < 2; ++nt) {
                int col = wn * 32 + nt * 16 + lm;
                float dot = (nt == 0) ? acc0[r] : acc1[r];
                float yn = kn_s[col];
                float diff = xn - 2.f * dot + yn;
                float den = fmaxf(fx * (1.f - cc * yn), EPSF);
                float arg = fmaf(2.f * cc * diff, __builtin_amdgcn_rcpf(den), 1.f);
                arg = fmaxf(arg, 1.f + EPSF);
                float dist = __logf(arg + sqrtf(arg * arg - 1.f)) * inv_sqrt_c;
                float p = __expf(fmaf(-beta_pos, dist, -bias));
                woutg[(bS + s0 + row) * S_ + t0 + col] = p;
                *(unsigned short*)(PsB + row * PSB + col * 2) = f2bf(p);
                if (nt == 0) p0 = p; else p1 = p;
            }
            lp[r] = p0 + p1;
        }
#pragma unroll
        for (int r = 0; r < 4; ++r) {
            float s = lp[r];
#pragma unroll
            for (int m = 1; m <= 8; m <<= 1) s += __shfl_xor(s, m, 64);
            if (lm == 0) atomicAdd(&l_row[wm * 16 + quad * 4 + r], s);
        }
        __syncthreads();

#pragma unroll
        for (int ks = 0; ks < 4; ++ks) {
            short8 ap = *(const short8*)(PsB + (wm * 16 + lm) * PSB + (ks * 32 + quad * 8) * 2);
            int d0 = wn * 32 + lm;
            int c = ks * 4 + quad;
            short8 v0 = *(const short8*)(VtB + d0 * 256 + ((c ^ (d0 & 7)) * 16));
            int d1 = d0 + 16;
            short8 v1 = *(const short8*)(VtB + d1 * 256 + ((c ^ (d1 & 7)) * 16));
            o0 = __builtin_amdgcn_mfma_f32_16x16x32_bf16(ap, v0, o0, 0, 0, 0);
            o1 = __builtin_amdgcn_mfma_f32_16x16x32_bf16(ap, v1, o1, 0, 0, 0);
        }
    }
    __syncthreads();

    float xs0[4], xs1[4];
#pragma unroll
    for (int r = 0; r < 4; ++r) {
        int row = wm * 16 + quad * 4 + r;
        float linv = __builtin_amdgcn_rcpf(l_row[row]);
        float x0 = o0[r] * linv, x1 = o1[r] * linv;
        xs0[r] = x0; xs1[r] = x1;
        float np = x0 * x0 + x1 * x1;
#pragma unroll
        for (int m = 1; m <= 8; m <<= 1) np += __shfl_xor(np, m, 64);
        if (lm == 0) atomicAdd(&nsq_s[row], np);
    }
    if (tid < 32) lws[bS + s0 + tid] = l_row[tid];
    __syncthreads();
#pragma unroll
    for (int r = 0; r < 4; ++r) {
        int row = wm * 16 + quad * 4 + r;
        float vn = fmaxf(sqrtf(nsq_s[row]), EPSF);
        float a = sqrt_c * vn;
        float th = 1.f - 2.f * __builtin_amdgcn_rcpf(__expf(2.f * a) + 1.f);
        float sc = th / a;
        houtg[(bS + s0 + row) * D_ + wn * 32 + lm] = xs0[r] * sc;
        houtg[(bS + s0 + row) * D_ + wn * 32 + 16 + lm] = xs1[r] * sc;
    }
}

__global__ __launch_bounds__(256) void wnorm_kernel(float* __restrict__ w,
                                                    const float* __restrict__ lws) {
    size_t idx = (size_t)blockIdx.x * 256 + threadIdx.x;
    int row = (int)(idx >> 9);
    float linv = 1.f / lws[row];
    float4* p = (float4*)w + idx;
    float4 v = *p;
    v.x *= linv; v.y *= linv; v.z *= linv; v.w *= linv;
    *p = v;
}

// ===================== launch =====================

extern "C" void kernel_launch(void* const* d_in, const int* in_sizes, int n_in,
                              void* d_out, int out_size, void* d_ws, size_t ws_size,
                              hipStream_t stream) {
    const float* q    = (const float*)d_in[0];
    const float* k    = (const float*)d_in[1];
    const float* v    = (const float*)d_in[2];
    const float* c    = (const float*)d_in[3];
    const float* beta = (const float*)d_in[4];
    const float* ab   = (const float*)d_in[5];

    float* out  = (float*)d_out;
    float* hout = out;                          // (B,S,D)
    float* wout = out + (size_t)B_ * S_ * D_;   // (B,S,S)

    float* qn  = (float*)d_ws;
    float* kn  = qn + B_ * S_;
    float* lws = kn + B_ * S_;
    char*  wsb = (char*)d_ws;
    const size_t QG_OFF = 98304;
    const size_t KG_OFF = QG_OFF + 65536;
    const size_t QB_OFF = KG_OFF + 65536;       // 229376
    const size_t KB_OFF = QB_OFF + 2097152;
    const size_t VT_OFF = KB_OFF + 2097152;
    const size_t NEED1  = VT_OFF + 2097152;
    const size_t OP_OFF = NEED1;
    const size_t PW_OFF = OP_OFF + 2u * B_ * S_ * D_ * 4;           // 8 MB partial O
    const size_t NEED2  = PW_OFF + (size_t)B_ * S_ * S_ * 2;        // 33.5 MB bf16 P

    float2*  qng = (float2*)(wsb + QG_OFF);
    float2*  kng = (float2*)(wsb + KG_OFF);
    unsigned* Qb = (unsigned*)(wsb + QB_OFF);
    unsigned* Kb = (unsigned*)(wsb + KB_OFF);
    uint4*   Vtb = (uint4*)(wsb + VT_OFF);

    if (ws_size >= NEED2) {
        float* Opart = (float*)(wsb + OP_OFF);
        uint4* Pws   = (uint4*)(wsb + PW_OFF);
        convqk_kernel<<<4096, 256, 0, stream>>>(q, k, c, qn, kn, lws, qng, kng, Qb, Kb);
        convv_kernel<<<64, 256, 0, stream>>>(v, Vtb);
        hattn3_kernel<<<512, 512, 0, stream>>>((const unsigned short*)Qb, (const char*)Kb,
                                               (const char*)Vtb, qng, kng, c, beta, ab,
                                               lws, Opart, Pws);
        hepi_kernel<<<2048, 256, 0, stream>>>(Opart, lws, c, hout);
        wnorm2_kernel<<<8192, 256, 0, stream>>>(Pws, lws, wout);
    } else {
        convqk_kernel<<<4096, 256, 0, stream>>>(q, k, c, qn, kn, lws, qng, kng, Qb, Kb);
        convv_kernel<<<64, 256, 0, stream>>>(v, Vtb);
        hattn_kernel<<<256, 512, 0, stream>>>((const unsigned short*)Qb, (const char*)Kb,
                                              (const char*)Vtb, qn, kn, c, beta, ab,
                                              lws, hout, wout);
        wnorm_kernel<<<(B_ * S_ * S_ / 4) / 256, 256, 0, stream>>>(wout, lws);
    }
}